// Round 13
// baseline (789.702 us; speedup 1.0000x reference)
//
#include <hip/hip_runtime.h>
#include <stdint.h>

#define B_ 8
#define S_ 2048
#define H_ 512
#define R_ 7
#define K_ 10
#define L_ 4
#define KT_ 4096  // fused K dim: 7 relation slices + self slice
#define RH_ 3584  // R*H

typedef __attribute__((ext_vector_type(8))) short bf16x8;
typedef __attribute__((ext_vector_type(4))) float f32x4;
typedef __attribute__((ext_vector_type(4))) unsigned short u16x4;
typedef unsigned long long u64;

__device__ __forceinline__ unsigned short f2bf(float f){
  unsigned int u = __float_as_uint(f);
  u = (u + 0x7fffu + ((u >> 16) & 1u)) >> 16;  // RNE
  return (unsigned short)u;
}

__device__ __forceinline__ float bf2f(unsigned short s){
  return __uint_as_float(((unsigned int)s) << 16);
}

__device__ __forceinline__ f32x4 bf4load(const unsigned short* p){
  u16x4 v = *(const u16x4*)p;
  f32x4 o;
#pragma unroll
  for (int e = 0; e < 4; e++) o[e] = bf2f(v[e]);
  return o;
}

__device__ __forceinline__ void gload16(const void* g, void* lds){
  __builtin_amdgcn_global_load_lds(
      (const __attribute__((address_space(1))) unsigned int*)g,
      (__attribute__((address_space(3))) unsigned int*)lds, 16, 0, 0);
}

// ---------------- KNN: per (b,i) find 10 nearest (excl self), exact f32 ops ---
// 4 i's per block (1 per wave). Per-lane top-6 (union of 64x6 sorted lists
// >= global top-10 unless one 32-elem j-stripe holds >=7 of a row's top-10).
__global__ __launch_bounds__(256) void knn_kernel(const float* __restrict__ pos,
                                                  int* __restrict__ knn){
  __shared__ float4 p4[S_];
  int b = blockIdx.y;
  const float* p = pos + (size_t)b * S_ * 3;
  for (int idx = threadIdx.x; idx < S_; idx += 256){
    float4 v; v.x = p[idx*3+0]; v.y = p[idx*3+1]; v.z = p[idx*3+2]; v.w = 0.f;
    p4[idx] = v;
  }
  __syncthreads();
  int w = threadIdx.x >> 6, l = threadIdx.x & 63;
  int i = blockIdx.x * 4 + w;
  float4 pi = p4[i];
  float xi = pi.x, yi = pi.y, zi = pi.z;
  u64 best[6];
#pragma unroll
  for (int q = 0; q < 6; q++) best[q] = ~0ull;
#pragma unroll 1
  for (int j = l; j < S_; j += 64){
    if (j == i) continue;
    float4 pj = p4[j];
    float dx = __fsub_rn(xi, pj.x);
    float dy = __fsub_rn(yi, pj.y);
    float dz = __fsub_rn(zi, pj.z);
    float d2 = __fadd_rn(__fadd_rn(__fmul_rn(dx,dx), __fmul_rn(dy,dy)), __fmul_rn(dz,dz));
    u64 key = ((u64)__float_as_uint(d2) << 32) | (unsigned)j;  // lex (d2, j)
    if (key < best[5]){
      best[5] = key;
#pragma unroll
      for (int q = 5; q > 0; --q){      // one bubble pass (rest sorted)
        u64 a = best[q-1], c = best[q];
        u64 lo = a < c ? a : c, hi = a < c ? c : a;
        best[q-1] = lo; best[q] = hi;
      }
    }
  }
  int* out = knn + ((size_t)b * S_ + i) * K_;
#pragma unroll
  for (int t = 0; t < 10; t++){
    u64 cand = best[0];
    u64 m = cand;
#pragma unroll
    for (int o = 32; o; o >>= 1){
      u64 other = __shfl_xor(m, o);
      if (other < m) m = other;
    }
    if (cand == m){
#pragma unroll
      for (int q = 0; q < 5; q++) best[q] = best[q+1];
      best[5] = ~0ull;
    }
    if (l == 0) out[t] = (int)(unsigned)(m & 0xffffffffu);
  }
}

// ---------------- CSR build (transpose KNN adjacency) -----------------------
__global__ void count_kernel(const int* __restrict__ knn, int* __restrict__ counts){
  int idx = blockIdx.x * 256 + threadIdx.x;     // B*S*K total
  int b = idx / (S_ * K_);
  int d = knn[idx];
  atomicAdd(&counts[b * S_ + d], 1);
}

__global__ __launch_bounds__(256) void scan_kernel(const int* __restrict__ counts,
                                                   int* __restrict__ row_start,
                                                   int* __restrict__ cursor){
  __shared__ int lds[256];
  int b = blockIdx.x, t = threadIdx.x;
  int base = b * S_;
  int v[8]; int s = 0;
#pragma unroll
  for (int e = 0; e < 8; e++){ v[e] = s; s += counts[base + t*8 + e]; }
  lds[t] = s;
  __syncthreads();
  int total = s;
  for (int o = 1; o < 256; o <<= 1){
    int add = 0;
    if (t >= o) add = lds[t - o];
    __syncthreads();
    lds[t] += add;
    __syncthreads();
  }
  int ex = lds[t] - total;
  int rb = b * (S_ + 1);
#pragma unroll
  for (int e = 0; e < 8; e++){
    int val = ex + v[e];
    row_start[rb + t*8 + e] = val;
    cursor[base + t*8 + e] = val;
  }
  if (t == 255) row_start[rb + S_] = lds[255];
}

__global__ void fill_kernel(const int* __restrict__ knn, int* __restrict__ cursor,
                            int* __restrict__ col){
  int idx = blockIdx.x * 256 + threadIdx.x;     // B*S*K
  int b = idx / (S_ * K_);
  int i = (idx / K_) % S_;
  int d = knn[idx];
  int p = atomicAdd(&cursor[b * S_ + d], 1);
  col[(size_t)b * S_ * K_ + p] = i;
}

__global__ void sort_kernel(const int* __restrict__ row_start, int* __restrict__ col){
  int idx = blockIdx.x * 256 + threadIdx.x;     // B*S
  int b = idx / S_, d = idx % S_;
  int rs = row_start[b*(S_+1)+d], re = row_start[b*(S_+1)+d+1];
  int* c = col + (size_t)b * S_ * K_;
  for (int a = rs + 1; a < re; ++a){
    int vv = c[a]; int q = a - 1;
    while (q >= rs && c[q] > vv){ c[q+1] = c[q]; --q; }
    c[q+1] = vv;
  }
}

// ---------------- weight prep: Wt[l][j=512][k=4096] = [Wlin[l][j] | Wself[l][j]]
__global__ void prepw_kernel(const float* __restrict__ Wlin, const float* __restrict__ Wself,
                             unsigned short* __restrict__ Wt){
  size_t e = ((size_t)blockIdx.x * 256 + threadIdx.x) * 8;   // L*512*4096 elements
  int k = (int)(e & 4095);
  int j = (int)((e >> 12) & 511);
  int l = (int)(e >> 21);
  const float* src = (k < RH_) ? Wlin + ((size_t)l * H_ + j) * RH_ + k
                               : Wself + ((size_t)l * H_ + j) * H_ + (k - RH_);
  union { unsigned short s[8]; uint4 u; } pk;
#pragma unroll
  for (int t = 0; t < 8; t++) pk.s[t] = f2bf(src[t]);
  *(uint4*)&Wt[e] = pk.u;
}

__global__ void prepa_kernel(const float* __restrict__ gam, const float* __restrict__ bet,
                             const float* __restrict__ mean, const float* __restrict__ var,
                             const float* __restrict__ blin, const float* __restrict__ bself,
                             float* __restrict__ scale, float* __restrict__ shift){
  int idx = blockIdx.x * 256 + threadIdx.x;     // L*H
  float sc = gam[idx] * rsqrtf(var[idx] + 1e-5f);
  scale[idx] = sc;
  shift[idx] = bet[idx] + (blin[idx] + bself[idx] - mean[idx]) * sc;
}

// ---------------- h0 = pos @ Wp.T + bp --------------------------------------
__global__ void inith_kernel(const float* __restrict__ pos, const float* __restrict__ Wp,
                             const float* __restrict__ bp, float* __restrict__ h,
                             unsigned short* __restrict__ hb){
  int idx = blockIdx.x * 256 + threadIdx.x;     // B*S*(H/4)
  int j = (idx & 127) * 4;
  int bs = idx >> 7;
  const float* p = pos + (size_t)bs * 3;
  float x = p[0], y = p[1], z = p[2];
  f32x4 o;
#pragma unroll
  for (int e = 0; e < 4; e++){
    const float* wr = Wp + (j + e) * 3;
    o[e] = x * wr[0] + y * wr[1] + z * wr[2] + bp[j + e];
  }
  *(f32x4*)&h[(size_t)bs * H_ + j] = o;
  unsigned int w0 = f2bf(o[0]) | ((unsigned)f2bf(o[1]) << 16);
  unsigned int w1 = f2bf(o[2]) | ((unsigned)f2bf(o[3]) << 16);
  uint2 u; u.x = w0; u.y = w1;
  *(uint2*)&hb[(size_t)bs * H_ + j] = u;
}

// ---------------- hknn[d] = sum_{i: d in knn(i)} hb[i]  (bf16 out) ----------
__global__ __launch_bounds__(256) void hknn_kernel(const unsigned short* __restrict__ hb,
                                                   const int* __restrict__ row_start,
                                                   const int* __restrict__ col,
                                                   unsigned short* __restrict__ hk){
  int w = threadIdx.x >> 6, l = threadIdx.x & 63;
  int d = blockIdx.x * 4 + w;
  int b = blockIdx.y;
  int rs = row_start[b * (S_ + 1) + d];
  int re = row_start[b * (S_ + 1) + d + 1];
  const int* cl = col + (size_t)b * S_ * K_;
  const unsigned short* base = hb + (size_t)b * S_ * H_ + l * 8;
  f32x4 aLo = {0,0,0,0}, aHi = {0,0,0,0}, bLo = {0,0,0,0}, bHi = {0,0,0,0};
  int e = rs;
  for (; e + 1 < re; e += 2){
    uint4 v0 = *(const uint4*)(base + (size_t)cl[e]     * H_);
    uint4 v1 = *(const uint4*)(base + (size_t)cl[e + 1] * H_);
    aLo[0] += __uint_as_float(v0.x << 16); aLo[1] += __uint_as_float(v0.x & 0xffff0000u);
    aLo[2] += __uint_as_float(v0.y << 16); aLo[3] += __uint_as_float(v0.y & 0xffff0000u);
    aHi[0] += __uint_as_float(v0.z << 16); aHi[1] += __uint_as_float(v0.z & 0xffff0000u);
    aHi[2] += __uint_as_float(v0.w << 16); aHi[3] += __uint_as_float(v0.w & 0xffff0000u);
    bLo[0] += __uint_as_float(v1.x << 16); bLo[1] += __uint_as_float(v1.x & 0xffff0000u);
    bLo[2] += __uint_as_float(v1.y << 16); bLo[3] += __uint_as_float(v1.y & 0xffff0000u);
    bHi[0] += __uint_as_float(v1.z << 16); bHi[1] += __uint_as_float(v1.z & 0xffff0000u);
    bHi[2] += __uint_as_float(v1.w << 16); bHi[3] += __uint_as_float(v1.w & 0xffff0000u);
  }
  if (e < re){
    uint4 v0 = *(const uint4*)(base + (size_t)cl[e] * H_);
    aLo[0] += __uint_as_float(v0.x << 16); aLo[1] += __uint_as_float(v0.x & 0xffff0000u);
    aLo[2] += __uint_as_float(v0.y << 16); aLo[3] += __uint_as_float(v0.y & 0xffff0000u);
    aHi[0] += __uint_as_float(v0.z << 16); aHi[1] += __uint_as_float(v0.z & 0xffff0000u);
    aHi[2] += __uint_as_float(v0.w << 16); aHi[3] += __uint_as_float(v0.w & 0xffff0000u);
  }
  aLo += bLo; aHi += bHi;
  uint4 o;
  o.x = f2bf(aLo[0]) | ((unsigned)f2bf(aLo[1]) << 16);
  o.y = f2bf(aLo[2]) | ((unsigned)f2bf(aLo[3]) << 16);
  o.z = f2bf(aHi[0]) | ((unsigned)f2bf(aHi[1]) << 16);
  o.w = f2bf(aHi[2]) | ((unsigned)f2bf(aHi[3]) << 16);
  *(uint4*)(hk + ((size_t)b * S_ + d) * H_ + l * 8) = o;
}

// ---------------- fused GEMM: out = [shifted-h slices | hknn | h] @ Wt.T ----
// M=16384, N=512, K=4096. BM=128, BN=256, BK=64 -> grid 256 (1 block/CU).
// 8 waves (2M x 4N) of 64x64. A-operand DIRECT-TO-REGISTER from L2 (inline-asm
// global_load_dwordx4, double-buffered one K-tile ahead, manual vmcnt gates);
// B via global_load_lds into 3-slot LDS ring (96 KB) with 8x16B XOR swizzle.
// Per K-tile: issue {4 B-stage(t+2), 8 A-load(t+1)} -> vmcnt(12) [A(t),B(t+1)
// landed] -> 8 B ds_reads (k-half groups) -> lgkm(4) MFMA kh0 -> lgkm(0)
// MFMA kh1 -> barrier. Epilogue: BN affine + relu + residual.
__global__ __launch_bounds__(512) void gemmf_kernel(
    const unsigned short* __restrict__ hbin,
    const unsigned short* __restrict__ hkn,
    const unsigned short* __restrict__ Wt,     // [512][4096] this layer
    float* __restrict__ h,
    unsigned short* __restrict__ hbout,
    const float* __restrict__ scale,           // [512] this layer
    const float* __restrict__ shift,
    const unsigned short* __restrict__ zbuf){
  __shared__ unsigned short Bs[3][256 * 64];   // 96 KB
  int tid = threadIdx.x;
  int wg = blockIdx.x;                 // 256 blocks
  int swz = (wg & 7) * 32 + (wg >> 3); // bijective XCD swizzle (256 % 8 == 0)
  int my = swz >> 1;                   // 128 M tiles
  int nx = swz & 1;                    // 2 N tiles
  int l = tid & 63, wid = tid >> 6;
  int wm = wid >> 2, wn = wid & 3;     // 2M x 4N waves of 64x64
  f32x4 acc[4][4] = {};

  // ---- B staging coords: 4 gload16/thread per K-tile ----
  int arow = tid >> 3;                               // 0..63
  int lA8 = ((tid & 7) ^ (arow & 7)) << 3;           // swizzled chunk * 8 elems
  const unsigned short* Bp0 = Wt + (size_t)(nx * 256 +   0 + arow) * KT_ + lA8;
  const unsigned short* Bp1 = Wt + (size_t)(nx * 256 +  64 + arow) * KT_ + lA8;
  const unsigned short* Bp2 = Wt + (size_t)(nx * 256 + 128 + arow) * KT_ + lA8;
  const unsigned short* Bp3 = Wt + (size_t)(nx * 256 + 192 + arow) * KT_ + lA8;
  int dB0 = tid * 8, dB1 = (512 + tid) * 8, dB2 = (1024 + tid) * 8, dB3 = (1536 + tid) * 8;

#define STAGEB(sl, kb) do {                                \
    gload16(Bp0 + (kb), &Bs[sl][dB0]);                     \
    gload16(Bp1 + (kb), &Bs[sl][dB1]);                     \
    gload16(Bp2 + (kb), &Bs[sl][dB2]);                     \
    gload16(Bp3 + (kb), &Bs[sl][dB3]);                     \
  } while (0)

  // ---- A-frag addressing: per-lane rows, per-slice pointers -------------
  int lr = l & 15, kcr = l >> 4, lr7 = l & 7;
  int graphid = (my * 128) >> 11;
  const unsigned short* pA[4];   // per mi; static-indexed only

#define SETSLC(rr) do {                                                       \
    int _r = (rr);                                                            \
    int _sh = (_r < 6) ? ((_r < 3) ? (3 - _r) : (2 - _r)) : 0;                \
    const unsigned short* _bb = (_r == 6) ? hkn : hbin;                       \
    _Pragma("unroll")                                                         \
    for (int _mi = 0; _mi < 4; _mi++){                                        \
      int _src = my * 128 + wm * 64 + _mi * 16 + lr + _sh;                    \
      bool _ok = (_r >= 6) || ((_src >> 11) == graphid);                      \
      pA[_mi] = (_ok ? _bb + (size_t)_src * H_ : zbuf) + kcr * 8;             \
    }                                                                         \
  } while (0)

#define LOADA(A, T) do {                                                      \
    int _ko = ((T) & 7) * 64;                                                 \
    _Pragma("unroll")                                                         \
    for (int _mi = 0; _mi < 4; _mi++){                                        \
      asm volatile("global_load_dwordx4 %0, %1, off"                          \
        : "=v"(A[_mi][0]) : "v"(pA[_mi] + _ko) : "memory");                   \
      asm volatile("global_load_dwordx4 %0, %1, off"                          \
        : "=v"(A[_mi][1]) : "v"(pA[_mi] + _ko + 32) : "memory");              \
    }                                                                         \
  } while (0)

  bf16x8 Ae[4][2], Ao[4][2];

  // ---- prologue ----
  SETSLC(0);
  STAGEB(0, 0);
  STAGEB(1, 64);
  LOADA(Ae, 0);
  asm volatile("s_waitcnt vmcnt(12)" ::: "memory");  // B(0) landed
  __builtin_amdgcn_s_barrier();
  asm volatile("" ::: "memory");

  int rB0 = wn * 64 + lr;
  int pc0 = (kcr ^ lr7) * 8;
  int pc1 = ((4 + kcr) ^ lr7) * 8;
  int s = 0;

#define TILE(T, ACUR, ANXT) do {                                              \
    int _t = (T);                                                             \
    int _s2 = s + 2; if (_s2 >= 3) _s2 -= 3;                                  \
    if (_t < 62) STAGEB(_s2, (_t + 2) * 64);                                  \
    if (_t < 63){                                                             \
      if (((_t + 1) & 7) == 0) SETSLC((_t + 1) >> 3);                         \
      LOADA(ANXT, _t + 1);                                                    \
    }                                                                         \
    if (_t < 62)       asm volatile("s_waitcnt vmcnt(12)" ::: "memory");      \
    else if (_t == 62) asm volatile("s_waitcnt vmcnt(8)" ::: "memory");       \
    else               asm volatile("s_waitcnt vmcnt(0)" ::: "memory");       \
    __builtin_amdgcn_sched_barrier(0);                                        \
    bf16x8 _bf0[4], _bf1[4];                                                  \
    _Pragma("unroll")                                                         \
    for (int _ni = 0; _ni < 4; _ni++)                                         \
      _bf0[_ni] = *(const bf16x8*)&Bs[s][(rB0 + _ni * 16) * 64 + pc0];        \
    __builtin_amdgcn_sched_barrier(0);                                        \
    _Pragma("unroll")                                                         \
    for (int _ni = 0; _ni < 4; _ni++)                                         \
      _bf1[_ni] = *(const bf16x8*)&Bs[s][(rB0 + _ni * 16) * 64 + pc1];        \
    __builtin_amdgcn_sched_barrier(0);                                        \
    asm volatile("s_waitcnt lgkmcnt(4)" ::: "memory");                        \
    __builtin_amdgcn_sched_barrier(0);                                        \
    __builtin_amdgcn_s_setprio(1);                                            \
    _Pragma("unroll")                                                         \
    for (int _mi = 0; _mi < 4; _mi++)                                         \
      _Pragma("unroll")                                                       \
      for (int _ni = 0; _ni < 4; _ni++)                                       \
        acc[_mi][_ni] = __builtin_amdgcn_mfma_f32_16x16x32_bf16(              \
            ACUR[_mi][0], _bf0[_ni], acc[_mi][_ni], 0, 0, 0);                 \
    __builtin_amdgcn_s_setprio(0);                                            \
    __builtin_amdgcn_sched_barrier(0);                                        \
    asm volatile("s_waitcnt lgkmcnt(0)" ::: "memory");                        \
    __builtin_amdgcn_sched_barrier(0);                                        \
    __builtin_amdgcn_s_setprio(1);                                            \
    _Pragma("unroll")                                                         \
    for (int _mi = 0; _mi < 4; _mi++)                                         \
      _Pragma("unroll")                                                       \
      for (int _ni = 0; _ni < 4; _ni++)                                       \
        acc[_mi][_ni] = __builtin_amdgcn_mfma_f32_16x16x32_bf16(              \
            ACUR[_mi][1], _bf1[_ni], acc[_mi][_ni], 0, 0, 0);                 \
    __builtin_amdgcn_s_setprio(0);                                            \
    asm volatile("" ::: "memory");                                            \
    if (_t < 63){                                                             \
      __builtin_amdgcn_s_barrier();                                           \
      asm volatile("" ::: "memory");                                          \
    }                                                                         \
    ++s; if (s == 3) s = 0;                                                   \
  } while (0)

#pragma unroll 1
  for (int tp = 0; tp < 32; ++tp){
    TILE(2 * tp,     Ae, Ao);
    TILE(2 * tp + 1, Ao, Ae);
  }
#undef TILE
#undef LOADA
#undef SETSLC
#undef STAGEB

  // ---- epilogue: BN affine + relu + residual ----
  int r0 = (l >> 4) * 4, c0 = l & 15;
#pragma unroll
  for (int ni = 0; ni < 4; ni++){
    int gcol = nx * 256 + wn * 64 + ni * 16 + c0;
    float sc = scale[gcol], sf = shift[gcol];
#pragma unroll
    for (int mi = 0; mi < 4; mi++){
#pragma unroll
      for (int reg = 0; reg < 4; reg++){
        int grow = my * 128 + wm * 64 + mi * 16 + r0 + reg;
        size_t o = (size_t)grow * H_ + gcol;
        float val = fmaxf(acc[mi][ni][reg] * sc + sf, 0.f);
        float hv = h[o] + val;
        h[o] = hv;
        hbout[o] = f2bf(hv);
      }
    }
  }
}

extern "C" void kernel_launch(void* const* d_in, const int* in_sizes, int n_in,
                              void* d_out, int out_size, void* d_ws, size_t ws_size,
                              hipStream_t stream){
  const float* ca    = (const float*)d_in[1];
  const float* Wp    = (const float*)d_in[3];
  const float* bp    = (const float*)d_in[4];
  const float* Wlin  = (const float*)d_in[5];
  const float* blin  = (const float*)d_in[6];
  const float* Wself = (const float*)d_in[7];
  const float* bself = (const float*)d_in[8];
  const float* gam   = (const float*)d_in[9];
  const float* bet   = (const float*)d_in[10];
  const float* mean  = (const float*)d_in[11];
  const float* var   = (const float*)d_in[12];
  float* h = (float*)d_out;

  char* ws = (char*)d_ws;
  size_t off = 0;
  auto alloc = [&](size_t bytes) -> char* {
    char* p = ws + off;
    off = (off + bytes + 255) & ~(size_t)255;
    return p;
  };
  int* knn       = (int*)alloc((size_t)B_ * S_ * K_ * 4);
  int* counts    = (int*)alloc((size_t)B_ * S_ * 4);
  int* row_start = (int*)alloc((size_t)B_ * (S_ + 1) * 4);
  int* cursor    = (int*)alloc((size_t)B_ * S_ * 4);
  int* col       = (int*)alloc((size_t)B_ * S_ * K_ * 4);
  unsigned short* Wt  = (unsigned short*)alloc((size_t)L_ * H_ * KT_ * 2);
  float* scale   = (float*)alloc((size_t)L_ * H_ * 4);
  float* shift   = (float*)alloc((size_t)L_ * H_ * 4);
  unsigned short* hbA = (unsigned short*)alloc((size_t)B_ * S_ * H_ * 2);
  unsigned short* hbB = (unsigned short*)alloc((size_t)B_ * S_ * H_ * 2);
  unsigned short* hkn = (unsigned short*)alloc((size_t)B_ * S_ * H_ * 2);
  unsigned short* zbuf = (unsigned short*)alloc(8192 * 2);

  hipMemsetAsync(counts, 0, (size_t)B_ * S_ * 4, stream);
  hipMemsetAsync(zbuf, 0, 8192 * 2, stream);
  knn_kernel<<<dim3(S_ / 4, B_), 256, 0, stream>>>(ca, knn);
  count_kernel<<<dim3(B_ * S_ * K_ / 256), 256, 0, stream>>>(knn, counts);
  scan_kernel<<<dim3(B_), 256, 0, stream>>>(counts, row_start, cursor);
  fill_kernel<<<dim3(B_ * S_ * K_ / 256), 256, 0, stream>>>(knn, cursor, col);
  sort_kernel<<<dim3(B_ * S_ / 256), 256, 0, stream>>>(row_start, col);
  prepw_kernel<<<dim3((int)((size_t)L_ * H_ * KT_ / 8 / 256)), 256, 0, stream>>>(Wlin, Wself, Wt);
  prepa_kernel<<<dim3(L_ * H_ / 256), 256, 0, stream>>>(gam, bet, mean, var, blin, bself, scale, shift);
  inith_kernel<<<dim3(B_ * S_ * (H_ / 4) / 256), 256, 0, stream>>>(ca, Wp, bp, h, hbA);

  for (int l = 0; l < L_; l++){
    unsigned short* in  = (l & 1) ? hbB : hbA;
    unsigned short* out = (l & 1) ? hbA : hbB;
    hknn_kernel<<<dim3(S_ / 4, B_), 256, 0, stream>>>(in, row_start, col, hkn);
    gemmf_kernel<<<dim3(256), 512, 0, stream>>>(
        in, hkn, Wt + (size_t)l * H_ * KT_, h, out,
        scale + l * H_, shift + l * H_, zbuf);
  }
}

// Round 14
// 527.030 us; speedup vs baseline: 1.4984x; 1.4984x over previous
//
#include <hip/hip_runtime.h>
#include <stdint.h>

#define B_ 8
#define S_ 2048
#define H_ 512
#define R_ 7
#define K_ 10
#define L_ 4
#define KT_ 4096  // fused K dim: 7 relation slices + self slice
#define RH_ 3584  // R*H

typedef __attribute__((ext_vector_type(8))) short bf16x8;
typedef __attribute__((ext_vector_type(4))) float f32x4;
typedef __attribute__((ext_vector_type(4))) unsigned short u16x4;
typedef unsigned long long u64;

__device__ __forceinline__ unsigned short f2bf(float f){
  unsigned int u = __float_as_uint(f);
  u = (u + 0x7fffu + ((u >> 16) & 1u)) >> 16;  // RNE
  return (unsigned short)u;
}

__device__ __forceinline__ float bf2f(unsigned short s){
  return __uint_as_float(((unsigned int)s) << 16);
}

__device__ __forceinline__ f32x4 bf4load(const unsigned short* p){
  u16x4 v = *(const u16x4*)p;
  f32x4 o;
#pragma unroll
  for (int e = 0; e < 4; e++) o[e] = bf2f(v[e]);
  return o;
}

__device__ __forceinline__ void gload16(const void* g, void* lds){
  __builtin_amdgcn_global_load_lds(
      (const __attribute__((address_space(1))) unsigned int*)g,
      (__attribute__((address_space(3))) unsigned int*)lds, 16, 0, 0);
}

// ---------------- KNN: per (b,i) find 10 nearest (excl self), exact f32 ops ---
// 4 i's per block (1 per wave). Per-lane top-6 (union of 64x6 sorted lists
// >= global top-10 unless one 32-elem j-stripe holds >=7 of a row's top-10).
__global__ __launch_bounds__(256) void knn_kernel(const float* __restrict__ pos,
                                                  int* __restrict__ knn){
  __shared__ float4 p4[S_];
  int b = blockIdx.y;
  const float* p = pos + (size_t)b * S_ * 3;
  for (int idx = threadIdx.x; idx < S_; idx += 256){
    float4 v; v.x = p[idx*3+0]; v.y = p[idx*3+1]; v.z = p[idx*3+2]; v.w = 0.f;
    p4[idx] = v;
  }
  __syncthreads();
  int w = threadIdx.x >> 6, l = threadIdx.x & 63;
  int i = blockIdx.x * 4 + w;
  float4 pi = p4[i];
  float xi = pi.x, yi = pi.y, zi = pi.z;
  u64 best[6];
#pragma unroll
  for (int q = 0; q < 6; q++) best[q] = ~0ull;
#pragma unroll 1
  for (int j = l; j < S_; j += 64){
    if (j == i) continue;
    float4 pj = p4[j];
    float dx = __fsub_rn(xi, pj.x);
    float dy = __fsub_rn(yi, pj.y);
    float dz = __fsub_rn(zi, pj.z);
    float d2 = __fadd_rn(__fadd_rn(__fmul_rn(dx,dx), __fmul_rn(dy,dy)), __fmul_rn(dz,dz));
    u64 key = ((u64)__float_as_uint(d2) << 32) | (unsigned)j;  // lex (d2, j)
    if (key < best[5]){
      best[5] = key;
#pragma unroll
      for (int q = 5; q > 0; --q){      // one bubble pass (rest sorted)
        u64 a = best[q-1], c = best[q];
        u64 lo = a < c ? a : c, hi = a < c ? c : a;
        best[q-1] = lo; best[q] = hi;
      }
    }
  }
  int* out = knn + ((size_t)b * S_ + i) * K_;
#pragma unroll
  for (int t = 0; t < 10; t++){
    u64 cand = best[0];
    u64 m = cand;
#pragma unroll
    for (int o = 32; o; o >>= 1){
      u64 other = __shfl_xor(m, o);
      if (other < m) m = other;
    }
    if (cand == m){
#pragma unroll
      for (int q = 0; q < 5; q++) best[q] = best[q+1];
      best[5] = ~0ull;
    }
    if (l == 0) out[t] = (int)(unsigned)(m & 0xffffffffu);
  }
}

// ---------------- CSR build (transpose KNN adjacency) -----------------------
__global__ void count_kernel(const int* __restrict__ knn, int* __restrict__ counts){
  int idx = blockIdx.x * 256 + threadIdx.x;     // B*S*K total
  int b = idx / (S_ * K_);
  int d = knn[idx];
  atomicAdd(&counts[b * S_ + d], 1);
}

__global__ __launch_bounds__(256) void scan_kernel(const int* __restrict__ counts,
                                                   int* __restrict__ row_start,
                                                   int* __restrict__ cursor){
  __shared__ int lds[256];
  int b = blockIdx.x, t = threadIdx.x;
  int base = b * S_;
  int v[8]; int s = 0;
#pragma unroll
  for (int e = 0; e < 8; e++){ v[e] = s; s += counts[base + t*8 + e]; }
  lds[t] = s;
  __syncthreads();
  int total = s;
  for (int o = 1; o < 256; o <<= 1){
    int add = 0;
    if (t >= o) add = lds[t - o];
    __syncthreads();
    lds[t] += add;
    __syncthreads();
  }
  int ex = lds[t] - total;
  int rb = b * (S_ + 1);
#pragma unroll
  for (int e = 0; e < 8; e++){
    int val = ex + v[e];
    row_start[rb + t*8 + e] = val;
    cursor[base + t*8 + e] = val;
  }
  if (t == 255) row_start[rb + S_] = lds[255];
}

__global__ void fill_kernel(const int* __restrict__ knn, int* __restrict__ cursor,
                            int* __restrict__ col){
  int idx = blockIdx.x * 256 + threadIdx.x;     // B*S*K
  int b = idx / (S_ * K_);
  int i = (idx / K_) % S_;
  int d = knn[idx];
  int p = atomicAdd(&cursor[b * S_ + d], 1);
  col[(size_t)b * S_ * K_ + p] = i;
}

__global__ void sort_kernel(const int* __restrict__ row_start, int* __restrict__ col){
  int idx = blockIdx.x * 256 + threadIdx.x;     // B*S
  int b = idx / S_, d = idx % S_;
  int rs = row_start[b*(S_+1)+d], re = row_start[b*(S_+1)+d+1];
  int* c = col + (size_t)b * S_ * K_;
  for (int a = rs + 1; a < re; ++a){
    int vv = c[a]; int q = a - 1;
    while (q >= rs && c[q] > vv){ c[q+1] = c[q]; --q; }
    c[q+1] = vv;
  }
}

// ---------------- weight prep: Wt[l][j=512][k=4096] = [Wlin[l][j] | Wself[l][j]]
__global__ void prepw_kernel(const float* __restrict__ Wlin, const float* __restrict__ Wself,
                             unsigned short* __restrict__ Wt){
  size_t e = ((size_t)blockIdx.x * 256 + threadIdx.x) * 8;   // L*512*4096 elements
  int k = (int)(e & 4095);
  int j = (int)((e >> 12) & 511);
  int l = (int)(e >> 21);
  const float* src = (k < RH_) ? Wlin + ((size_t)l * H_ + j) * RH_ + k
                               : Wself + ((size_t)l * H_ + j) * H_ + (k - RH_);
  union { unsigned short s[8]; uint4 u; } pk;
#pragma unroll
  for (int t = 0; t < 8; t++) pk.s[t] = f2bf(src[t]);
  *(uint4*)&Wt[e] = pk.u;
}

__global__ void prepa_kernel(const float* __restrict__ gam, const float* __restrict__ bet,
                             const float* __restrict__ mean, const float* __restrict__ var,
                             const float* __restrict__ blin, const float* __restrict__ bself,
                             float* __restrict__ scale, float* __restrict__ shift){
  int idx = blockIdx.x * 256 + threadIdx.x;     // L*H
  float sc = gam[idx] * rsqrtf(var[idx] + 1e-5f);
  scale[idx] = sc;
  shift[idx] = bet[idx] + (blin[idx] + bself[idx] - mean[idx]) * sc;
}

// ---------------- h0 = pos @ Wp.T + bp --------------------------------------
__global__ void inith_kernel(const float* __restrict__ pos, const float* __restrict__ Wp,
                             const float* __restrict__ bp, float* __restrict__ h,
                             unsigned short* __restrict__ hb){
  int idx = blockIdx.x * 256 + threadIdx.x;     // B*S*(H/4)
  int j = (idx & 127) * 4;
  int bs = idx >> 7;
  const float* p = pos + (size_t)bs * 3;
  float x = p[0], y = p[1], z = p[2];
  f32x4 o;
#pragma unroll
  for (int e = 0; e < 4; e++){
    const float* wr = Wp + (j + e) * 3;
    o[e] = x * wr[0] + y * wr[1] + z * wr[2] + bp[j + e];
  }
  *(f32x4*)&h[(size_t)bs * H_ + j] = o;
  unsigned int w0 = f2bf(o[0]) | ((unsigned)f2bf(o[1]) << 16);
  unsigned int w1 = f2bf(o[2]) | ((unsigned)f2bf(o[3]) << 16);
  uint2 u; u.x = w0; u.y = w1;
  *(uint2*)&hb[(size_t)bs * H_ + j] = u;
}

// ---------------- hknn[d] = sum_{i: d in knn(i)} hb[i]  (bf16 out) ----------
// wave-per-row: 64 lanes x bf16x8 = 512 cols; 4 rows per 256-thr block;
// uniform CSR indices -> scalar loads; 2-way unrolled accumulators.
__global__ __launch_bounds__(256) void hknn_kernel(const unsigned short* __restrict__ hb,
                                                   const int* __restrict__ row_start,
                                                   const int* __restrict__ col,
                                                   unsigned short* __restrict__ hk){
  int w = threadIdx.x >> 6, l = threadIdx.x & 63;
  int d = blockIdx.x * 4 + w;
  int b = blockIdx.y;
  int rs = row_start[b * (S_ + 1) + d];
  int re = row_start[b * (S_ + 1) + d + 1];
  const int* cl = col + (size_t)b * S_ * K_;
  const unsigned short* base = hb + (size_t)b * S_ * H_ + l * 8;
  f32x4 aLo = {0,0,0,0}, aHi = {0,0,0,0}, bLo = {0,0,0,0}, bHi = {0,0,0,0};
  int e = rs;
  for (; e + 1 < re; e += 2){
    uint4 v0 = *(const uint4*)(base + (size_t)cl[e]     * H_);
    uint4 v1 = *(const uint4*)(base + (size_t)cl[e + 1] * H_);
    aLo[0] += __uint_as_float(v0.x << 16); aLo[1] += __uint_as_float(v0.x & 0xffff0000u);
    aLo[2] += __uint_as_float(v0.y << 16); aLo[3] += __uint_as_float(v0.y & 0xffff0000u);
    aHi[0] += __uint_as_float(v0.z << 16); aHi[1] += __uint_as_float(v0.z & 0xffff0000u);
    aHi[2] += __uint_as_float(v0.w << 16); aHi[3] += __uint_as_float(v0.w & 0xffff0000u);
    bLo[0] += __uint_as_float(v1.x << 16); bLo[1] += __uint_as_float(v1.x & 0xffff0000u);
    bLo[2] += __uint_as_float(v1.y << 16); bLo[3] += __uint_as_float(v1.y & 0xffff0000u);
    bHi[0] += __uint_as_float(v1.z << 16); bHi[1] += __uint_as_float(v1.z & 0xffff0000u);
    bHi[2] += __uint_as_float(v1.w << 16); bHi[3] += __uint_as_float(v1.w & 0xffff0000u);
  }
  if (e < re){
    uint4 v0 = *(const uint4*)(base + (size_t)cl[e] * H_);
    aLo[0] += __uint_as_float(v0.x << 16); aLo[1] += __uint_as_float(v0.x & 0xffff0000u);
    aLo[2] += __uint_as_float(v0.y << 16); aLo[3] += __uint_as_float(v0.y & 0xffff0000u);
    aHi[0] += __uint_as_float(v0.z << 16); aHi[1] += __uint_as_float(v0.z & 0xffff0000u);
    aHi[2] += __uint_as_float(v0.w << 16); aHi[3] += __uint_as_float(v0.w & 0xffff0000u);
  }
  aLo += bLo; aHi += bHi;
  uint4 o;
  o.x = f2bf(aLo[0]) | ((unsigned)f2bf(aLo[1]) << 16);
  o.y = f2bf(aLo[2]) | ((unsigned)f2bf(aLo[3]) << 16);
  o.z = f2bf(aHi[0]) | ((unsigned)f2bf(aHi[1]) << 16);
  o.w = f2bf(aHi[2]) | ((unsigned)f2bf(aHi[3]) << 16);
  *(uint4*)(hk + ((size_t)b * S_ + d) * H_ + l * 8) = o;
}

// ---------------- fused GEMM: out = [shifted-h slices | hknn | h] @ Wt.T ----
// M=16384, N=512, K=4096. BM=128, BN=256, BK=64 -> grid 256 (1 block/CU).
// 8 waves (2M x 4N) of 64x64 (4x4 frags). 3-slot LDS ring (144 KB), prefetch
// depth 2 K-tiles, counted vmcnt(6). k-half intra-wave pipeline. ONE barrier
// per K-tile: vmcnt placed just before the end barrier serves both WAR
// (reads of slot s done before t+1's STAGE overwrites it) and RAW (tile t+1
// landed before t+1's reads).
// 8x16B chunk XOR swizzle (phys = logical ^ (row&7)) via pre-swizzled source.
// Epilogue: BN affine + relu + residual.
__global__ __launch_bounds__(512) void gemmf_kernel(
    const unsigned short* __restrict__ hbin,
    const unsigned short* __restrict__ hkn,
    const unsigned short* __restrict__ Wt,     // [512][4096] this layer
    float* __restrict__ h,
    unsigned short* __restrict__ hbout,
    const float* __restrict__ scale,           // [512] this layer
    const float* __restrict__ shift,
    const unsigned short* __restrict__ zbuf){
  __shared__ unsigned short As[3][128 * 64];   // 48 KB
  __shared__ unsigned short Bs[3][256 * 64];   // 96 KB
  int tid = threadIdx.x;
  int wg = blockIdx.x;                 // 256 blocks
  int swz = (wg & 7) * 32 + (wg >> 3); // bijective XCD swizzle (256 % 8 == 0)
  int my = swz >> 1;                   // 128 M tiles
  int nx = swz & 1;                    // 2 N tiles
  int l = tid & 63, wid = tid >> 6;
  int wm = wid >> 2, wn = wid & 3;     // 2M x 4N waves of 64x64
  f32x4 acc[4][4] = {};

  // ---- staging coords: A 2 loads/thread, B 4 loads/thread per K-tile ----
  int arow = tid >> 3;                               // 0..63
  int lA8 = ((tid & 7) ^ (arow & 7)) << 3;           // logical chunk * 8 (elems)
  int gr0 = my * 128 + arow, gr1 = gr0 + 64;
  const unsigned short* Bp0 = Wt + (size_t)(nx * 256 +   0 + arow) * KT_ + lA8;
  const unsigned short* Bp1 = Wt + (size_t)(nx * 256 +  64 + arow) * KT_ + lA8;
  const unsigned short* Bp2 = Wt + (size_t)(nx * 256 + 128 + arow) * KT_ + lA8;
  const unsigned short* Bp3 = Wt + (size_t)(nx * 256 + 192 + arow) * KT_ + lA8;
  const unsigned short *sa0, *sa1;

#define SETSLC(rr) do {                                                       \
    int _r = (rr);                                                            \
    const unsigned short *_b0, *_b1;                                          \
    if (_r < 6){                                                              \
      int _sh = (_r < 3) ? (3 - _r) : (2 - _r);    /* src = d - off_r */      \
      int _s0 = gr0 + _sh, _s1 = gr1 + _sh;                                   \
      _b0 = (((unsigned)_s0 >> 11) == ((unsigned)gr0 >> 11)) ? hbin + (size_t)_s0 * H_ : zbuf; \
      _b1 = (((unsigned)_s1 >> 11) == ((unsigned)gr1 >> 11)) ? hbin + (size_t)_s1 * H_ : zbuf; \
    } else {                                                                  \
      const unsigned short* _bb = (_r == 6) ? hkn : hbin;                     \
      _b0 = _bb + (size_t)gr0 * H_; _b1 = _bb + (size_t)gr1 * H_;             \
    }                                                                         \
    sa0 = _b0 + lA8; sa1 = _b1 + lA8;                                         \
  } while (0)

  int dA0 = tid * 8, dA1 = (512 + tid) * 8;
  int dB0 = tid * 8, dB1 = (512 + tid) * 8, dB2 = (1024 + tid) * 8, dB3 = (1536 + tid) * 8;

#define STAGE(sl, ko, kb) do {                             \
    gload16(sa0 + (ko), &As[sl][dA0]);                     \
    gload16(sa1 + (ko), &As[sl][dA1]);                     \
    gload16(Bp0 + (kb), &Bs[sl][dB0]);                     \
    gload16(Bp1 + (kb), &Bs[sl][dB1]);                     \
    gload16(Bp2 + (kb), &Bs[sl][dB2]);                     \
    gload16(Bp3 + (kb), &Bs[sl][dB3]);                     \
  } while (0)

  // ---- prologue: stage tiles 0 and 1 (both slice 0) ----
  SETSLC(0);
  STAGE(0, 0, 0);
  STAGE(1, 64, 64);
  asm volatile("s_waitcnt vmcnt(6)" ::: "memory");   // tile 0 landed
  __builtin_amdgcn_s_barrier();
  asm volatile("" ::: "memory");

  int kcr = l >> 4, lr = l & 15, lr7 = l & 7;
  int rA0 = wm * 64 + lr, rB0 = wn * 64 + lr;
  int pc0 = (kcr ^ lr7) * 8;
  int pc1 = ((4 + kcr) ^ lr7) * 8;
  int s = 0;
#pragma unroll 1
  for (int t = 0; t < 64; ++t){
    int s2 = s + 2; if (s2 >= 3) s2 -= 3;
    int tt = t + 2;
    bool st = (t < 62);
    if (st) SETSLC(tt >> 3);

    // 16 ds_read_b128, grouped by k-half (order pinned)
    bf16x8 af0[4], af1[4], bf0[4], bf1[4];
#pragma unroll
    for (int mi = 0; mi < 4; mi++)
      af0[mi] = *(const bf16x8*)&As[s][(rA0 + mi * 16) * 64 + pc0];
#pragma unroll
    for (int ni = 0; ni < 4; ni++)
      bf0[ni] = *(const bf16x8*)&Bs[s][(rB0 + ni * 16) * 64 + pc0];
    __builtin_amdgcn_sched_barrier(0);
#pragma unroll
    for (int mi = 0; mi < 4; mi++)
      af1[mi] = *(const bf16x8*)&As[s][(rA0 + mi * 16) * 64 + pc1];
#pragma unroll
    for (int ni = 0; ni < 4; ni++)
      bf1[ni] = *(const bf16x8*)&Bs[s][(rB0 + ni * 16) * 64 + pc1];
    __builtin_amdgcn_sched_barrier(0);

    // half-0 frags landed (8 of 16 still outstanding)
    asm volatile("s_waitcnt lgkmcnt(8)" ::: "memory");
    __builtin_amdgcn_sched_barrier(0);
    __builtin_amdgcn_s_setprio(1);
#pragma unroll
    for (int mi = 0; mi < 4; mi++)
#pragma unroll
      for (int ni = 0; ni < 4; ni++)
        acc[mi][ni] = __builtin_amdgcn_mfma_f32_16x16x32_bf16(af0[mi], bf0[ni], acc[mi][ni], 0, 0, 0);
    __builtin_amdgcn_s_setprio(0);
    __builtin_amdgcn_sched_barrier(0);

    // issue tile t+2's staging under half-1's drain
    if (st) STAGE(s2, (tt & 7) * 64, tt * 64);

    asm volatile("s_waitcnt lgkmcnt(0)" ::: "memory");
    __builtin_amdgcn_sched_barrier(0);
    __builtin_amdgcn_s_setprio(1);
#pragma unroll
    for (int mi = 0; mi < 4; mi++)
#pragma unroll
      for (int ni = 0; ni < 4; ni++)
        acc[mi][ni] = __builtin_amdgcn_mfma_f32_16x16x32_bf16(af1[mi], bf1[ni], acc[mi][ni], 0, 0, 0);
    __builtin_amdgcn_s_setprio(0);
    asm volatile("" ::: "memory");

    // single end barrier: tile t+1 landed + all reads of slot s done
    if (t < 62)       asm volatile("s_waitcnt vmcnt(6)" ::: "memory");
    else if (t == 62) asm volatile("s_waitcnt vmcnt(0)" ::: "memory");
    if (t < 63){
      __builtin_amdgcn_s_barrier();
      asm volatile("" ::: "memory");
    }
    ++s; if (s == 3) s = 0;
  }
#undef STAGE
#undef SETSLC

  // ---- epilogue: BN affine + relu + residual ----
  int r0 = (l >> 4) * 4, c0 = l & 15;
#pragma unroll
  for (int ni = 0; ni < 4; ni++){
    int gcol = nx * 256 + wn * 64 + ni * 16 + c0;
    float sc = scale[gcol], sf = shift[gcol];
#pragma unroll
    for (int mi = 0; mi < 4; mi++){
#pragma unroll
      for (int reg = 0; reg < 4; reg++){
        int grow = my * 128 + wm * 64 + mi * 16 + r0 + reg;
        size_t o = (size_t)grow * H_ + gcol;
        float val = fmaxf(acc[mi][ni][reg] * sc + sf, 0.f);
        float hv = h[o] + val;
        h[o] = hv;
        hbout[o] = f2bf(hv);
      }
    }
  }
}

extern "C" void kernel_launch(void* const* d_in, const int* in_sizes, int n_in,
                              void* d_out, int out_size, void* d_ws, size_t ws_size,
                              hipStream_t stream){
  const float* ca    = (const float*)d_in[1];
  const float* Wp    = (const float*)d_in[3];
  const float* bp    = (const float*)d_in[4];
  const float* Wlin  = (const float*)d_in[5];
  const float* blin  = (const float*)d_in[6];
  const float* Wself = (const float*)d_in[7];
  const float* bself = (const float*)d_in[8];
  const float* gam   = (const float*)d_in[9];
  const float* bet   = (const float*)d_in[10];
  const float* mean  = (const float*)d_in[11];
  const float* var   = (const float*)d_in[12];
  float* h = (float*)d_out;

  char* ws = (char*)d_ws;
  size_t off = 0;
  auto alloc = [&](size_t bytes) -> char* {
    char* p = ws + off;
    off = (off + bytes + 255) & ~(size_t)255;
    return p;
  };
  int* knn       = (int*)alloc((size_t)B_ * S_ * K_ * 4);
  int* counts    = (int*)alloc((size_t)B_ * S_ * 4);
  int* row_start = (int*)alloc((size_t)B_ * (S_ + 1) * 4);
  int* cursor    = (int*)alloc((size_t)B_ * S_ * 4);
  int* col       = (int*)alloc((size_t)B_ * S_ * K_ * 4);
  unsigned short* Wt  = (unsigned short*)alloc((size_t)L_ * H_ * KT_ * 2);
  float* scale   = (float*)alloc((size_t)L_ * H_ * 4);
  float* shift   = (float*)alloc((size_t)L_ * H_ * 4);
  unsigned short* hbA = (unsigned short*)alloc((size_t)B_ * S_ * H_ * 2);
  unsigned short* hbB = (unsigned short*)alloc((size_t)B_ * S_ * H_ * 2);
  unsigned short* hkn = (unsigned short*)alloc((size_t)B_ * S_ * H_ * 2);
  unsigned short* zbuf = (unsigned short*)alloc(4096 * 2);

  hipMemsetAsync(counts, 0, (size_t)B_ * S_ * 4, stream);
  hipMemsetAsync(zbuf, 0, 4096 * 2, stream);
  knn_kernel<<<dim3(S_ / 4, B_), 256, 0, stream>>>(ca, knn);
  count_kernel<<<dim3(B_ * S_ * K_ / 256), 256, 0, stream>>>(knn, counts);
  scan_kernel<<<dim3(B_), 256, 0, stream>>>(counts, row_start, cursor);
  fill_kernel<<<dim3(B_ * S_ * K_ / 256), 256, 0, stream>>>(knn, cursor, col);
  sort_kernel<<<dim3(B_ * S_ / 256), 256, 0, stream>>>(row_start, col);
  prepw_kernel<<<dim3((int)((size_t)L_ * H_ * KT_ / 8 / 256)), 256, 0, stream>>>(Wlin, Wself, Wt);
  prepa_kernel<<<dim3(L_ * H_ / 256), 256, 0, stream>>>(gam, bet, mean, var, blin, bself, scale, shift);
  inith_kernel<<<dim3(B_ * S_ * (H_ / 4) / 256), 256, 0, stream>>>(ca, Wp, bp, h, hbA);

  for (int l = 0; l < L_; l++){
    unsigned short* in  = (l & 1) ? hbB : hbA;
    unsigned short* out = (l & 1) ? hbA : hbB;
    hknn_kernel<<<dim3(S_ / 4, B_), 256, 0, stream>>>(in, row_start, col, hkn);
    gemmf_kernel<<<dim3(256), 512, 0, stream>>>(
        in, hkn, Wt + (size_t)l * H_ * KT_, h, out,
        scale + l * H_, shift + l * H_, zbuf);
  }
}